// Round 1
// baseline (9173.609 us; speedup 1.0000x reference)
//
#include <hip/hip_runtime.h>

#define NN 100000
#define EE 1600000

// ---------------- degree / dinv ----------------
__global__ __launch_bounds__(256) void k_deg_init(unsigned int* deg) {
    int v = blockIdx.x * 256 + threadIdx.x;
    if (v < NN) deg[v] = 1u;
}

__global__ __launch_bounds__(256) void k_deg_count(const int* __restrict__ dst, unsigned int* deg) {
    int e = blockIdx.x * 256 + threadIdx.x;
    if (e < EE) atomicAdd(&deg[dst[e]], 1u);
}

__global__ __launch_bounds__(256) void k_dinv(float* dinv) {
    int v = blockIdx.x * 256 + threadIdx.x;
    if (v < NN) {
        unsigned int d = ((const unsigned int*)dinv)[v];
        dinv[v] = rsqrtf((float)d);
    }
}

// ---------------- GEMM1: g1 = (x @ Wg1) * dinv[row]; acc1 = g1 (self loop) ----
// block 256 thr, tile 64 nodes x 64 cols, K=1024 chunked by 64
__global__ __launch_bounds__(256) void k_gemm1(const float* __restrict__ x,
        const float* __restrict__ W, const float* __restrict__ dinv,
        float* __restrict__ g1, float* __restrict__ acc1) {
    __shared__ __align__(16) float xs[64][68];
    __shared__ __align__(16) float wsh[64][64];
    const int tid = threadIdx.x;
    const int tx = tid & 15, ty = tid >> 4;
    const int node0 = blockIdx.x * 64;
    const int lr = tid >> 4;
    const int lk = (tid & 15) * 4;
    float acc[4][4] = {{0.f}};
    for (int kc = 0; kc < 1024; kc += 64) {
        #pragma unroll
        for (int l = 0; l < 4; ++l) {
            int r = lr + l * 16;
            int v = node0 + r;
            float4 xv = make_float4(0.f, 0.f, 0.f, 0.f);
            if (v < NN) xv = *(const float4*)(x + (size_t)v * 1024 + kc + lk);
            *(float4*)&xs[r][lk] = xv;
            *(float4*)&wsh[r][lk] = *(const float4*)(W + (size_t)(kc + r) * 64 + lk);
        }
        __syncthreads();
        for (int kk = 0; kk < 64; kk += 4) {
            float wv[4][4];
            #pragma unroll
            for (int j = 0; j < 4; ++j)
                *(float4*)&wv[j][0] = *(const float4*)&wsh[kk + j][tx * 4];
            #pragma unroll
            for (int i = 0; i < 4; ++i) {
                float xv[4];
                *(float4*)&xv[0] = *(const float4*)&xs[ty * 4 + i][kk];
                #pragma unroll
                for (int j = 0; j < 4; ++j) {
                    #pragma unroll
                    for (int c = 0; c < 4; ++c)
                        acc[i][c] += xv[j] * wv[j][c];
                }
            }
        }
        __syncthreads();
    }
    #pragma unroll
    for (int i = 0; i < 4; ++i) {
        int v = node0 + ty * 4 + i;
        if (v < NN) {
            float di = dinv[v];
            float4 o;
            o.x = acc[i][0] * di; o.y = acc[i][1] * di;
            o.z = acc[i][2] * di; o.w = acc[i][3] * di;
            *(float4*)(g1 + (size_t)v * 64 + tx * 4) = o;
            *(float4*)(acc1 + (size_t)v * 64 + tx * 4) = o;
        }
    }
}

// ---------------- edge scatter, 64 ch: acc[dst] += g[src] ----------------
__global__ __launch_bounds__(256) void k_scatter64(const int* __restrict__ src,
        const int* __restrict__ dst, const float* __restrict__ g, float* __restrict__ acc) {
    unsigned int gid = blockIdx.x * 256 + threadIdx.x;
    unsigned int e = gid >> 2;
    if (e >= EE) return;
    int part = gid & 3;
    int s = src[e], d = dst[e];
    const float* gp = g + (size_t)s * 64 + part * 16;
    float* ap = acc + (size_t)d * 64 + part * 16;
    #pragma unroll
    for (int q = 0; q < 4; ++q) {
        float4 v = *(const float4*)(gp + q * 4);
        unsafeAtomicAdd(ap + q * 4 + 0, v.x);
        unsafeAtomicAdd(ap + q * 4 + 1, v.y);
        unsafeAtomicAdd(ap + q * 4 + 2, v.z);
        unsafeAtomicAdd(ap + q * 4 + 3, v.w);
    }
}

// ---------------- layer2: a1=relu(dinv*acc1+bg1); g2=(a1@Wg2)*dinv; acc2=g2 --
__global__ __launch_bounds__(256) void k_layer2(const float* __restrict__ acc1,
        const float* __restrict__ Wg2, const float* __restrict__ bg1,
        const float* __restrict__ dinv,
        float* __restrict__ g2, float* __restrict__ acc2) {
    __shared__ __align__(16) float as[64][68];
    __shared__ __align__(16) float wsh[64][32];
    const int tid = threadIdx.x;
    const int node0 = blockIdx.x * 64;
    {
        const int lr = tid >> 4, lk = (tid & 15) * 4;
        float4 b4 = *(const float4*)(bg1 + lk);
        #pragma unroll
        for (int l = 0; l < 4; ++l) {
            int r = lr + l * 16, v = node0 + r;
            float4 a = make_float4(0.f, 0.f, 0.f, 0.f);
            if (v < NN) {
                float di = dinv[v];
                float4 t = *(const float4*)(acc1 + (size_t)v * 64 + lk);
                a.x = fmaxf(t.x * di + b4.x, 0.f);
                a.y = fmaxf(t.y * di + b4.y, 0.f);
                a.z = fmaxf(t.z * di + b4.z, 0.f);
                a.w = fmaxf(t.w * di + b4.w, 0.f);
            }
            *(float4*)&as[r][lk] = a;
        }
        const int wr = tid >> 3, wk = (tid & 7) * 4;
        #pragma unroll
        for (int l = 0; l < 2; ++l) {
            int r = wr + l * 32;
            *(float4*)&wsh[r][wk] = *(const float4*)(Wg2 + (size_t)r * 32 + wk);
        }
    }
    __syncthreads();
    const int tx = tid & 7, ty = tid >> 3;
    float acc[2][4] = {{0.f}};
    for (int kk = 0; kk < 64; kk += 4) {
        float wv[4][4];
        #pragma unroll
        for (int j = 0; j < 4; ++j)
            *(float4*)&wv[j][0] = *(const float4*)&wsh[kk + j][tx * 4];
        #pragma unroll
        for (int i = 0; i < 2; ++i) {
            float xv[4];
            *(float4*)&xv[0] = *(const float4*)&as[ty * 2 + i][kk];
            #pragma unroll
            for (int j = 0; j < 4; ++j) {
                #pragma unroll
                for (int c = 0; c < 4; ++c)
                    acc[i][c] += xv[j] * wv[j][c];
            }
        }
    }
    #pragma unroll
    for (int i = 0; i < 2; ++i) {
        int v = node0 + ty * 2 + i;
        if (v < NN) {
            float di = dinv[v];
            float4 o;
            o.x = acc[i][0] * di; o.y = acc[i][1] * di;
            o.z = acc[i][2] * di; o.w = acc[i][3] * di;
            *(float4*)(g2 + (size_t)v * 32 + tx * 4) = o;
            *(float4*)(acc2 + (size_t)v * 32 + tx * 4) = o;
        }
    }
}

// ---------------- edge scatter, 32 ch ----------------
__global__ __launch_bounds__(256) void k_scatter32(const int* __restrict__ src,
        const int* __restrict__ dst, const float* __restrict__ g, float* __restrict__ acc) {
    unsigned int gid = blockIdx.x * 256 + threadIdx.x;
    unsigned int e = gid >> 1;
    if (e >= EE) return;
    int part = gid & 1;
    int s = src[e], d = dst[e];
    const float* gp = g + (size_t)s * 32 + part * 16;
    float* ap = acc + (size_t)d * 32 + part * 16;
    #pragma unroll
    for (int q = 0; q < 4; ++q) {
        float4 v = *(const float4*)(gp + q * 4);
        unsafeAtomicAdd(ap + q * 4 + 0, v.x);
        unsafeAtomicAdd(ap + q * 4 + 1, v.y);
        unsafeAtomicAdd(ap + q * 4 + 2, v.z);
        unsafeAtomicAdd(ap + q * 4 + 3, v.w);
    }
}

// ---------------- final: z -> d=relu(z@Wf1+bf1) -> out=relu(d@Wf2+bf2) ------
__global__ __launch_bounds__(256) void k_final(const float* __restrict__ acc2,
        const float* __restrict__ dinv, const float* __restrict__ bg2,
        const float* __restrict__ Wf1, const float* __restrict__ bf1,
        const float* __restrict__ Wf2, const float* __restrict__ bf2,
        float* __restrict__ out) {
    __shared__ __align__(16) float zs[64][36];
    __shared__ __align__(16) float dsh[64][68];
    __shared__ __align__(16) float w1s[32][64];
    __shared__ __align__(16) float w2s[64][68];
    const int tid = threadIdx.x;
    const int node0 = blockIdx.x * 64;
    // step 1: z = dinv*acc2 + bg2 (no relu); stage Wf1
    {
        const int zr = tid >> 3, zk = (tid & 7) * 4;
        float4 b4 = *(const float4*)(bg2 + zk);
        #pragma unroll
        for (int l = 0; l < 2; ++l) {
            int r = zr + l * 32, v = node0 + r;
            float4 z = make_float4(0.f, 0.f, 0.f, 0.f);
            if (v < NN) {
                float di = dinv[v];
                float4 t = *(const float4*)(acc2 + (size_t)v * 32 + zk);
                z.x = t.x * di + b4.x; z.y = t.y * di + b4.y;
                z.z = t.z * di + b4.z; z.w = t.w * di + b4.w;
            }
            *(float4*)&zs[r][zk] = z;
        }
        const int wr = tid >> 4, wk = (tid & 15) * 4;
        #pragma unroll
        for (int l = 0; l < 2; ++l) {
            int r = wr + l * 16;
            *(float4*)&w1s[r][wk] = *(const float4*)(Wf1 + (size_t)r * 64 + wk);
        }
    }
    __syncthreads();
    const int tx = tid & 15, ty = tid >> 4;
    // step 2: d = relu(z @ Wf1 + bf1)
    {
        float acc[4][4] = {{0.f}};
        for (int kk = 0; kk < 32; kk += 4) {
            float wv[4][4];
            #pragma unroll
            for (int j = 0; j < 4; ++j)
                *(float4*)&wv[j][0] = *(const float4*)&w1s[kk + j][tx * 4];
            #pragma unroll
            for (int i = 0; i < 4; ++i) {
                float zv[4];
                *(float4*)&zv[0] = *(const float4*)&zs[ty * 4 + i][kk];
                #pragma unroll
                for (int j = 0; j < 4; ++j) {
                    #pragma unroll
                    for (int c = 0; c < 4; ++c)
                        acc[i][c] += zv[j] * wv[j][c];
                }
            }
        }
        float4 b4 = *(const float4*)(bf1 + tx * 4);
        #pragma unroll
        for (int i = 0; i < 4; ++i) {
            float4 dd;
            dd.x = fmaxf(acc[i][0] + b4.x, 0.f);
            dd.y = fmaxf(acc[i][1] + b4.y, 0.f);
            dd.z = fmaxf(acc[i][2] + b4.z, 0.f);
            dd.w = fmaxf(acc[i][3] + b4.w, 0.f);
            *(float4*)&dsh[ty * 4 + i][tx * 4] = dd;
        }
    }
    __syncthreads();
    // step 3: out = relu(d @ Wf2 + bf2), 16 chunks of 64 cols
    const int lr = tid >> 4, lk = (tid & 15) * 4;
    for (int ch = 0; ch < 16; ++ch) {
        int col0 = ch * 64;
        #pragma unroll
        for (int l = 0; l < 4; ++l) {
            int r = lr + l * 16;
            *(float4*)&w2s[r][lk] = *(const float4*)(Wf2 + (size_t)r * 1024 + col0 + lk);
        }
        __syncthreads();
        float acc[4][4] = {{0.f}};
        for (int kk = 0; kk < 64; kk += 4) {
            float wv[4][4];
            #pragma unroll
            for (int j = 0; j < 4; ++j)
                *(float4*)&wv[j][0] = *(const float4*)&w2s[kk + j][tx * 4];
            #pragma unroll
            for (int i = 0; i < 4; ++i) {
                float dv[4];
                *(float4*)&dv[0] = *(const float4*)&dsh[ty * 4 + i][kk];
                #pragma unroll
                for (int j = 0; j < 4; ++j) {
                    #pragma unroll
                    for (int c = 0; c < 4; ++c)
                        acc[i][c] += dv[j] * wv[j][c];
                }
            }
        }
        float4 b4 = *(const float4*)(bf2 + col0 + tx * 4);
        #pragma unroll
        for (int i = 0; i < 4; ++i) {
            int v = node0 + ty * 4 + i;
            if (v < NN) {
                float4 o;
                o.x = fmaxf(acc[i][0] + b4.x, 0.f);
                o.y = fmaxf(acc[i][1] + b4.y, 0.f);
                o.z = fmaxf(acc[i][2] + b4.z, 0.f);
                o.w = fmaxf(acc[i][3] + b4.w, 0.f);
                *(float4*)(out + (size_t)v * 1024 + col0 + tx * 4) = o;
            }
        }
        __syncthreads();
    }
}

extern "C" void kernel_launch(void* const* d_in, const int* in_sizes, int n_in,
                              void* d_out, int out_size, void* d_ws, size_t ws_size,
                              hipStream_t stream) {
    const float* x   = (const float*)d_in[0];
    const int* ei    = (const int*)d_in[1];
    const float* Wg1 = (const float*)d_in[2];
    const float* bg1 = (const float*)d_in[3];
    const float* Wg2 = (const float*)d_in[4];
    const float* bg2 = (const float*)d_in[5];
    const float* Wf1 = (const float*)d_in[6];
    const float* bf1 = (const float*)d_in[7];
    const float* Wf2 = (const float*)d_in[8];
    const float* bf2 = (const float*)d_in[9];
    float* out = (float*)d_out;
    float* ws  = (float*)d_ws;

    const int* src = ei;
    const int* dst = ei + EE;

    float* dinv = ws;                          // N floats (deg as uint first)
    float* g2   = ws + NN;                     // 32N
    float* acc2 = ws + NN + 32 * NN;           // 32N
    float* g1   = out;                         // 64N (scratch inside d_out)
    float* acc1 = out + (size_t)64 * NN;       // 64N (scratch inside d_out)

    k_deg_init<<<(NN + 255) / 256, 256, 0, stream>>>((unsigned int*)dinv);
    k_deg_count<<<(EE + 255) / 256, 256, 0, stream>>>(dst, (unsigned int*)dinv);
    k_dinv<<<(NN + 255) / 256, 256, 0, stream>>>(dinv);
    k_gemm1<<<(NN + 63) / 64, 256, 0, stream>>>(x, Wg1, dinv, g1, acc1);
    k_scatter64<<<(EE * 4 + 255) / 256, 256, 0, stream>>>(src, dst, g1, acc1);
    k_layer2<<<(NN + 63) / 64, 256, 0, stream>>>(acc1, Wg2, bg1, dinv, g2, acc2);
    k_scatter32<<<(EE * 2 + 255) / 256, 256, 0, stream>>>(src, dst, g2, acc2);
    k_final<<<(NN + 63) / 64, 256, 0, stream>>>(acc2, dinv, bg2, Wf1, bf1, Wf2, bf2, out);
}

// Round 3
// 1183.131 us; speedup vs baseline: 7.7537x; 7.7537x over previous
//
#include <hip/hip_runtime.h>

#define NN 100000
#define EE 1600000

// ---------------- degree count (no self loop; +1 applied in dinv) ----------
__global__ __launch_bounds__(256) void k_init(unsigned int* cnt) {
    int v = blockIdx.x * 256 + threadIdx.x;
    if (v < NN) cnt[v] = 0u;
}

__global__ __launch_bounds__(256) void k_count(const int* __restrict__ dst, unsigned int* cnt) {
    int e = blockIdx.x * 256 + threadIdx.x;
    if (e < EE) atomicAdd(&cnt[dst[e]], 1u);
}

__global__ __launch_bounds__(256) void k_dinv(const unsigned int* __restrict__ cnt, float* dinv) {
    int v = blockIdx.x * 256 + threadIdx.x;
    if (v < NN) dinv[v] = rsqrtf((float)(cnt[v] + 1u));
}

// ---------------- exclusive prefix scan (single workgroup, shfl-based) -----
__global__ __launch_bounds__(1024) void k_scan(const unsigned int* __restrict__ cnt,
        unsigned int* __restrict__ row_ptr, unsigned int* __restrict__ cursor) {
    __shared__ unsigned int wsum[16];
    __shared__ unsigned int carry_s;
    const int tid = threadIdx.x;
    const int lane = tid & 63, w = tid >> 6;
    if (tid == 0) carry_s = 0u;
    __syncthreads();
    for (int base = 0; base < NN; base += 1024) {
        int i = base + tid;
        unsigned int v = (i < NN) ? cnt[i] : 0u;
        unsigned int incl = v;
        #pragma unroll
        for (int off = 1; off < 64; off <<= 1) {
            unsigned int t = __shfl_up(incl, off, 64);
            if (lane >= off) incl += t;
        }
        if (lane == 63) wsum[w] = incl;
        __syncthreads();
        unsigned int woff = 0;
        #pragma unroll
        for (int j = 0; j < 16; ++j) woff += (j < w) ? wsum[j] : 0u;
        unsigned int c = carry_s;
        if (i < NN) {
            unsigned int excl = c + woff + incl - v;
            row_ptr[i] = excl;
            cursor[i] = excl;
        }
        __syncthreads();
        if (tid == 1023) carry_s = c + woff + incl;
        __syncthreads();
    }
}

// ---------------- CSR fill: csr_src grouped by dst ----------------
__global__ __launch_bounds__(256) void k_fill(const int* __restrict__ src,
        const int* __restrict__ dst, unsigned int* cursor, int* __restrict__ csr_src) {
    int e = blockIdx.x * 256 + threadIdx.x;
    if (e < EE) {
        int d = dst[e];
        unsigned int pos = atomicAdd(&cursor[d], 1u);
        csr_src[pos] = src[e];
    }
}

// ---------------- GEMM1: g1 = (x @ Wg1) * dinv[row] ----------------
__global__ __launch_bounds__(256) void k_gemm1(const float* __restrict__ x,
        const float* __restrict__ W, const float* __restrict__ dinv,
        float* __restrict__ g1) {
    __shared__ __align__(16) float xs[64][68];
    __shared__ __align__(16) float wsh[64][64];
    const int tid = threadIdx.x;
    const int tx = tid & 15, ty = tid >> 4;
    const int node0 = blockIdx.x * 64;
    const int lr = tid >> 4;
    const int lk = (tid & 15) * 4;
    float acc[4][4] = {{0.f}};
    for (int kc = 0; kc < 1024; kc += 64) {
        #pragma unroll
        for (int l = 0; l < 4; ++l) {
            int r = lr + l * 16;
            int v = node0 + r;
            float4 xv = make_float4(0.f, 0.f, 0.f, 0.f);
            if (v < NN) xv = *(const float4*)(x + (size_t)v * 1024 + kc + lk);
            *(float4*)&xs[r][lk] = xv;
            *(float4*)&wsh[r][lk] = *(const float4*)(W + (size_t)(kc + r) * 64 + lk);
        }
        __syncthreads();
        for (int kk = 0; kk < 64; kk += 4) {
            float wv[4][4];
            #pragma unroll
            for (int j = 0; j < 4; ++j)
                *(float4*)&wv[j][0] = *(const float4*)&wsh[kk + j][tx * 4];
            #pragma unroll
            for (int i = 0; i < 4; ++i) {
                float xv[4];
                *(float4*)&xv[0] = *(const float4*)&xs[ty * 4 + i][kk];
                #pragma unroll
                for (int j = 0; j < 4; ++j) {
                    #pragma unroll
                    for (int c = 0; c < 4; ++c)
                        acc[i][c] += xv[j] * wv[j][c];
                }
            }
        }
        __syncthreads();
    }
    #pragma unroll
    for (int i = 0; i < 4; ++i) {
        int v = node0 + ty * 4 + i;
        if (v < NN) {
            float di = dinv[v];
            float4 o;
            o.x = acc[i][0] * di; o.y = acc[i][1] * di;
            o.z = acc[i][2] * di; o.w = acc[i][3] * di;
            *(float4*)(g1 + (size_t)v * 64 + tx * 4) = o;
        }
    }
}

// ------- gather 64ch + fused norm/bias/relu: h[v] = relu(dinv*(g1[v]+Σg1[nbr])+bg1)
__global__ __launch_bounds__(256) void k_gather64(const float* __restrict__ g1,
        const int* __restrict__ csr, const unsigned int* __restrict__ row_ptr,
        const unsigned int* __restrict__ cnt, const float* __restrict__ dinv,
        const float* __restrict__ bg1, float* __restrict__ h) {
    int wv = (blockIdx.x * 256 + threadIdx.x) >> 6;   // wave = node
    int lane = threadIdx.x & 63;
    if (wv >= NN) return;
    unsigned int s0 = row_ptr[wv];
    unsigned int n = cnt[wv];
    float sum = g1[(size_t)wv * 64 + lane];           // self loop
    unsigned int i = s0, end = s0 + n;
    for (; i + 2 <= end; i += 2) {
        int a = csr[i], b = csr[i + 1];
        float va = g1[(size_t)a * 64 + lane];
        float vb = g1[(size_t)b * 64 + lane];
        sum += va + vb;
    }
    if (i < end) sum += g1[(size_t)csr[i] * 64 + lane];
    h[(size_t)wv * 64 + lane] = fmaxf(sum * dinv[wv] + bg1[lane], 0.f);
}

// ---------------- layer2 GEMM: g2 = (h @ Wg2) * dinv[row] ----------------
__global__ __launch_bounds__(256) void k_layer2(const float* __restrict__ h,
        const float* __restrict__ Wg2, const float* __restrict__ dinv,
        float* __restrict__ g2) {
    __shared__ __align__(16) float as[64][68];
    __shared__ __align__(16) float wsh[64][32];
    const int tid = threadIdx.x;
    const int node0 = blockIdx.x * 64;
    {
        const int lr = tid >> 4, lk = (tid & 15) * 4;
        #pragma unroll
        for (int l = 0; l < 4; ++l) {
            int r = lr + l * 16, v = node0 + r;
            float4 a = make_float4(0.f, 0.f, 0.f, 0.f);
            if (v < NN) a = *(const float4*)(h + (size_t)v * 64 + lk);
            *(float4*)&as[r][lk] = a;
        }
        const int wr = tid >> 3, wk = (tid & 7) * 4;
        #pragma unroll
        for (int l = 0; l < 2; ++l) {
            int r = wr + l * 32;
            *(float4*)&wsh[r][wk] = *(const float4*)(Wg2 + (size_t)r * 32 + wk);
        }
    }
    __syncthreads();
    const int tx = tid & 7, ty = tid >> 3;
    float acc[2][4] = {{0.f}};
    for (int kk = 0; kk < 64; kk += 4) {
        float wv[4][4];
        #pragma unroll
        for (int j = 0; j < 4; ++j)
            *(float4*)&wv[j][0] = *(const float4*)&wsh[kk + j][tx * 4];
        #pragma unroll
        for (int i = 0; i < 2; ++i) {
            float xv[4];
            *(float4*)&xv[0] = *(const float4*)&as[ty * 2 + i][kk];
            #pragma unroll
            for (int j = 0; j < 4; ++j) {
                #pragma unroll
                for (int c = 0; c < 4; ++c)
                    acc[i][c] += xv[j] * wv[j][c];
            }
        }
    }
    #pragma unroll
    for (int i = 0; i < 2; ++i) {
        int v = node0 + ty * 2 + i;
        if (v < NN) {
            float di = dinv[v];
            float4 o;
            o.x = acc[i][0] * di; o.y = acc[i][1] * di;
            o.z = acc[i][2] * di; o.w = acc[i][3] * di;
            *(float4*)(g2 + (size_t)v * 32 + tx * 4) = o;
        }
    }
}

// ------- gather 32ch + fused norm/bias: z[v] = dinv*(g2[v]+Σg2[nbr]) + bg2
__global__ __launch_bounds__(256) void k_gather32(const float* __restrict__ g2,
        const int* __restrict__ csr, const unsigned int* __restrict__ row_ptr,
        const unsigned int* __restrict__ cnt, const float* __restrict__ dinv,
        const float* __restrict__ bg2, float* __restrict__ z) {
    int node = (blockIdx.x * 256 + threadIdx.x) >> 5;  // half-wave = node
    int c = threadIdx.x & 31;
    if (node >= NN) return;
    unsigned int s0 = row_ptr[node];
    unsigned int n = cnt[node];
    float sum = g2[(size_t)node * 32 + c];
    unsigned int i = s0, end = s0 + n;
    for (; i + 2 <= end; i += 2) {
        int a = csr[i], b = csr[i + 1];
        float va = g2[(size_t)a * 32 + c];
        float vb = g2[(size_t)b * 32 + c];
        sum += va + vb;
    }
    if (i < end) sum += g2[(size_t)csr[i] * 32 + c];
    z[(size_t)node * 32 + c] = sum * dinv[node] + bg2[c];
}

// ---------------- final: z -> d=relu(z@Wf1+bf1) -> out=relu(d@Wf2+bf2) ------
__global__ __launch_bounds__(256) void k_final(const float* __restrict__ z,
        const float* __restrict__ Wf1, const float* __restrict__ bf1,
        const float* __restrict__ Wf2, const float* __restrict__ bf2,
        float* __restrict__ out) {
    __shared__ __align__(16) float zs[64][36];
    __shared__ __align__(16) float dsh[64][68];
    __shared__ __align__(16) float w1s[32][64];
    __shared__ __align__(16) float w2s[64][68];
    const int tid = threadIdx.x;
    const int node0 = blockIdx.x * 64;
    // step 1: stage z and Wf1
    {
        const int zr = tid >> 3, zk = (tid & 7) * 4;
        #pragma unroll
        for (int l = 0; l < 2; ++l) {
            int r = zr + l * 32, v = node0 + r;
            float4 zz = make_float4(0.f, 0.f, 0.f, 0.f);
            if (v < NN) zz = *(const float4*)(z + (size_t)v * 32 + zk);
            *(float4*)&zs[r][zk] = zz;
        }
        const int wr = tid >> 4, wk = (tid & 15) * 4;
        #pragma unroll
        for (int l = 0; l < 2; ++l) {
            int r = wr + l * 16;
            *(float4*)&w1s[r][wk] = *(const float4*)(Wf1 + (size_t)r * 64 + wk);
        }
    }
    __syncthreads();
    const int tx = tid & 15, ty = tid >> 4;
    // step 2: d = relu(z @ Wf1 + bf1)
    {
        float acc[4][4] = {{0.f}};
        for (int kk = 0; kk < 32; kk += 4) {
            float wv[4][4];
            #pragma unroll
            for (int j = 0; j < 4; ++j)
                *(float4*)&wv[j][0] = *(const float4*)&w1s[kk + j][tx * 4];
            #pragma unroll
            for (int i = 0; i < 4; ++i) {
                float zv[4];
                *(float4*)&zv[0] = *(const float4*)&zs[ty * 4 + i][kk];
                #pragma unroll
                for (int j = 0; j < 4; ++j) {
                    #pragma unroll
                    for (int c = 0; c < 4; ++c)
                        acc[i][c] += zv[j] * wv[j][c];
                }
            }
        }
        float4 b4 = *(const float4*)(bf1 + tx * 4);
        #pragma unroll
        for (int i = 0; i < 4; ++i) {
            float4 dd;
            dd.x = fmaxf(acc[i][0] + b4.x, 0.f);
            dd.y = fmaxf(acc[i][1] + b4.y, 0.f);
            dd.z = fmaxf(acc[i][2] + b4.z, 0.f);
            dd.w = fmaxf(acc[i][3] + b4.w, 0.f);
            *(float4*)&dsh[ty * 4 + i][tx * 4] = dd;
        }
    }
    __syncthreads();
    // step 3: out = relu(d @ Wf2 + bf2), 16 chunks of 64 cols
    const int lr = tid >> 4, lk = (tid & 15) * 4;
    for (int ch = 0; ch < 16; ++ch) {
        int col0 = ch * 64;
        #pragma unroll
        for (int l = 0; l < 4; ++l) {
            int r = lr + l * 16;
            *(float4*)&w2s[r][lk] = *(const float4*)(Wf2 + (size_t)r * 1024 + col0 + lk);
        }
        __syncthreads();
        float acc[4][4] = {{0.f}};
        for (int kk = 0; kk < 64; kk += 4) {
            float wv[4][4];
            #pragma unroll
            for (int j = 0; j < 4; ++j)
                *(float4*)&wv[j][0] = *(const float4*)&w2s[kk + j][tx * 4];
            #pragma unroll
            for (int i = 0; i < 4; ++i) {
                float dv[4];
                *(float4*)&dv[0] = *(const float4*)&dsh[ty * 4 + i][kk];
                #pragma unroll
                for (int j = 0; j < 4; ++j) {
                    #pragma unroll
                    for (int c = 0; c < 4; ++c)
                        acc[i][c] += dv[j] * wv[j][c];
                }
            }
        }
        float4 b4 = *(const float4*)(bf2 + col0 + tx * 4);
        #pragma unroll
        for (int i = 0; i < 4; ++i) {
            int v = node0 + ty * 4 + i;
            if (v < NN) {
                float4 o;
                o.x = fmaxf(acc[i][0] + b4.x, 0.f);
                o.y = fmaxf(acc[i][1] + b4.y, 0.f);
                o.z = fmaxf(acc[i][2] + b4.z, 0.f);
                o.w = fmaxf(acc[i][3] + b4.w, 0.f);
                *(float4*)(out + (size_t)v * 1024 + col0 + tx * 4) = o;
            }
        }
        __syncthreads();
    }
}

extern "C" void kernel_launch(void* const* d_in, const int* in_sizes, int n_in,
                              void* d_out, int out_size, void* d_ws, size_t ws_size,
                              hipStream_t stream) {
    const float* x   = (const float*)d_in[0];
    const int* ei    = (const int*)d_in[1];
    const float* Wg1 = (const float*)d_in[2];
    const float* bg1 = (const float*)d_in[3];
    const float* Wg2 = (const float*)d_in[4];
    const float* bg2 = (const float*)d_in[5];
    const float* Wf1 = (const float*)d_in[6];
    const float* bf1 = (const float*)d_in[7];
    const float* Wf2 = (const float*)d_in[8];
    const float* bf2 = (const float*)d_in[9];
    float* out = (float*)d_out;
    float* ws  = (float*)d_ws;

    const int* src = ei;
    const int* dst = ei + EE;

    // ws scratch (26 MB): dinv | g2 | z
    float* dinv = ws;
    float* g2   = ws + NN;
    float* z    = ws + NN + 32 * NN;

    // d_out spare space used as scratch (all overwritten by k_final):
    float* g1 = out;                                  // 64N floats
    float* h  = out + (size_t)64 * NN;                // 64N floats
    int*      csr_src = (int*)(out + (size_t)128 * NN);        // E ints
    unsigned int* cnt     = (unsigned int*)(csr_src + EE);      // N
    unsigned int* row_ptr = cnt + NN;                           // N
    unsigned int* cursor  = row_ptr + NN;                       // N

    k_init  <<<(NN + 255) / 256, 256, 0, stream>>>(cnt);
    k_count <<<(EE + 255) / 256, 256, 0, stream>>>(dst, cnt);
    k_dinv  <<<(NN + 255) / 256, 256, 0, stream>>>(cnt, dinv);
    k_scan  <<<1, 1024, 0, stream>>>(cnt, row_ptr, cursor);
    k_fill  <<<(EE + 255) / 256, 256, 0, stream>>>(src, dst, cursor, csr_src);
    k_gemm1 <<<(NN + 63) / 64, 256, 0, stream>>>(x, Wg1, dinv, g1);
    k_gather64<<<(NN * 64 + 255) / 256, 256, 0, stream>>>(g1, csr_src, row_ptr, cnt, dinv, bg1, h);
    k_layer2<<<(NN + 63) / 64, 256, 0, stream>>>(h, Wg2, dinv, g2);
    k_gather32<<<(NN * 32 + 255) / 256, 256, 0, stream>>>(g2, csr_src, row_ptr, cnt, dinv, bg2, z);
    k_final <<<(NN + 63) / 64, 256, 0, stream>>>(z, Wf1, bf1, Wf2, bf2, out);
}

// Round 4
// 1029.350 us; speedup vs baseline: 8.9120x; 1.1494x over previous
//
#include <hip/hip_runtime.h>

#define NN 100000
#define EE 1600000

// ---------------- degree count (no self loop; +1 applied in dinv) ----------
__global__ __launch_bounds__(256) void k_init(unsigned int* cnt) {
    int v = blockIdx.x * 256 + threadIdx.x;
    if (v < NN) cnt[v] = 0u;
}

__global__ __launch_bounds__(256) void k_count(const int* __restrict__ dst, unsigned int* cnt) {
    int e = blockIdx.x * 256 + threadIdx.x;
    if (e < EE) atomicAdd(&cnt[dst[e]], 1u);
}

__global__ __launch_bounds__(256) void k_dinv(const unsigned int* __restrict__ cnt, float* dinv) {
    int v = blockIdx.x * 256 + threadIdx.x;
    if (v < NN) dinv[v] = rsqrtf((float)(cnt[v] + 1u));
}

// ---------------- exclusive prefix scan (single workgroup, shfl-based) -----
__global__ __launch_bounds__(1024) void k_scan(const unsigned int* __restrict__ cnt,
        unsigned int* __restrict__ row_ptr, unsigned int* __restrict__ cursor) {
    __shared__ unsigned int wsum[16];
    __shared__ unsigned int carry_s;
    const int tid = threadIdx.x;
    const int lane = tid & 63, w = tid >> 6;
    if (tid == 0) carry_s = 0u;
    __syncthreads();
    for (int base = 0; base < NN; base += 1024) {
        int i = base + tid;
        unsigned int v = (i < NN) ? cnt[i] : 0u;
        unsigned int incl = v;
        #pragma unroll
        for (int off = 1; off < 64; off <<= 1) {
            unsigned int t = __shfl_up(incl, off, 64);
            if (lane >= off) incl += t;
        }
        if (lane == 63) wsum[w] = incl;
        __syncthreads();
        unsigned int woff = 0;
        #pragma unroll
        for (int j = 0; j < 16; ++j) woff += (j < w) ? wsum[j] : 0u;
        unsigned int c = carry_s;
        if (i < NN) {
            unsigned int excl = c + woff + incl - v;
            row_ptr[i] = excl;
            cursor[i] = excl;
        }
        __syncthreads();
        if (tid == 1023) carry_s = c + woff + incl;
        __syncthreads();
    }
}

// ---------------- CSR fill: csr_src grouped by dst ----------------
__global__ __launch_bounds__(256) void k_fill(const int* __restrict__ src,
        const int* __restrict__ dst, unsigned int* cursor, int* __restrict__ csr_src) {
    int e = blockIdx.x * 256 + threadIdx.x;
    if (e < EE) {
        int d = dst[e];
        unsigned int pos = atomicAdd(&cursor[d], 1u);
        csr_src[pos] = src[e];
    }
}

// ---------------- GEMM1: g1 = (x @ Wg1) * dinv[row] ----------------
// 128-node x 64-col tile, K chunks of 64; per-thread 8n x 4c.
__global__ __launch_bounds__(256) void k_gemm1(const float* __restrict__ x,
        const float* __restrict__ W, const float* __restrict__ dinv,
        float* __restrict__ g1) {
    __shared__ __align__(16) float xs[128][68];
    __shared__ __align__(16) float wsh[64][64];
    const int tid = threadIdx.x;
    const int tx = tid & 15, ty = tid >> 4;   // tx: col4, ty: node group
    const int node0 = blockIdx.x * 128;
    float acc[8][4] = {{0.f}};
    for (int kc = 0; kc < 1024; kc += 64) {
        // stage x[128][64]: 2048 float4, 8 per thread
        #pragma unroll
        for (int j = 0; j < 8; ++j) {
            int fi = tid + 256 * j;
            int v = fi >> 4, k4 = (fi & 15) * 4;
            float4 xv = make_float4(0.f, 0.f, 0.f, 0.f);
            if (node0 + v < NN) xv = *(const float4*)(x + (size_t)(node0 + v) * 1024 + kc + k4);
            *(float4*)&xs[v][k4] = xv;
        }
        // stage W[64][64]: 1024 float4, 4 per thread
        #pragma unroll
        for (int j = 0; j < 4; ++j) {
            int fi = tid + 256 * j;
            int r = fi >> 4, c4 = (fi & 15) * 4;
            *(float4*)&wsh[r][c4] = *(const float4*)(W + (size_t)(kc + r) * 64 + c4);
        }
        __syncthreads();
        for (int kk = 0; kk < 64; kk += 4) {
            float wv[4][4];
            #pragma unroll
            for (int j = 0; j < 4; ++j)
                *(float4*)&wv[j][0] = *(const float4*)&wsh[kk + j][tx * 4];
            #pragma unroll
            for (int i = 0; i < 8; ++i) {
                float xv[4];
                *(float4*)&xv[0] = *(const float4*)&xs[ty * 8 + i][kk];
                #pragma unroll
                for (int j = 0; j < 4; ++j) {
                    #pragma unroll
                    for (int c = 0; c < 4; ++c)
                        acc[i][c] += xv[j] * wv[j][c];
                }
            }
        }
        __syncthreads();
    }
    #pragma unroll
    for (int i = 0; i < 8; ++i) {
        int v = node0 + ty * 8 + i;
        if (v < NN) {
            float di = dinv[v];
            float4 o;
            o.x = acc[i][0] * di; o.y = acc[i][1] * di;
            o.z = acc[i][2] * di; o.w = acc[i][3] * di;
            *(float4*)(g1 + (size_t)v * 64 + tx * 4) = o;
        }
    }
}

// ------- gather 64ch + fused norm/bias/relu: h[v] = relu(dinv*(g1[v]+Σg1[nbr])+bg1)
__global__ __launch_bounds__(256) void k_gather64(const float* __restrict__ g1,
        const int* __restrict__ csr, const unsigned int* __restrict__ row_ptr,
        const unsigned int* __restrict__ cnt, const float* __restrict__ dinv,
        const float* __restrict__ bg1, float* __restrict__ h) {
    int wv = (blockIdx.x * 256 + threadIdx.x) >> 6;   // wave = node
    int lane = threadIdx.x & 63;
    if (wv >= NN) return;
    unsigned int s0 = row_ptr[wv];
    unsigned int n = cnt[wv];
    float sum = g1[(size_t)wv * 64 + lane];           // self loop
    unsigned int i = s0, end = s0 + n;
    for (; i + 2 <= end; i += 2) {
        int a = csr[i], b = csr[i + 1];
        float va = g1[(size_t)a * 64 + lane];
        float vb = g1[(size_t)b * 64 + lane];
        sum += va + vb;
    }
    if (i < end) sum += g1[(size_t)csr[i] * 64 + lane];
    h[(size_t)wv * 64 + lane] = fmaxf(sum * dinv[wv] + bg1[lane], 0.f);
}

// ---------------- layer2 GEMM: g2 = (h @ Wg2) * dinv[row] ----------------
__global__ __launch_bounds__(256) void k_layer2(const float* __restrict__ h,
        const float* __restrict__ Wg2, const float* __restrict__ dinv,
        float* __restrict__ g2) {
    __shared__ __align__(16) float as[64][68];
    __shared__ __align__(16) float wsh[64][32];
    const int tid = threadIdx.x;
    const int node0 = blockIdx.x * 64;
    {
        const int lr = tid >> 4, lk = (tid & 15) * 4;
        #pragma unroll
        for (int l = 0; l < 4; ++l) {
            int r = lr + l * 16, v = node0 + r;
            float4 a = make_float4(0.f, 0.f, 0.f, 0.f);
            if (v < NN) a = *(const float4*)(h + (size_t)v * 64 + lk);
            *(float4*)&as[r][lk] = a;
        }
        const int wr = tid >> 3, wk = (tid & 7) * 4;
        #pragma unroll
        for (int l = 0; l < 2; ++l) {
            int r = wr + l * 32;
            *(float4*)&wsh[r][wk] = *(const float4*)(Wg2 + (size_t)r * 32 + wk);
        }
    }
    __syncthreads();
    const int tx = tid & 7, ty = tid >> 3;
    float acc[2][4] = {{0.f}};
    for (int kk = 0; kk < 64; kk += 4) {
        float wv[4][4];
        #pragma unroll
        for (int j = 0; j < 4; ++j)
            *(float4*)&wv[j][0] = *(const float4*)&wsh[kk + j][tx * 4];
        #pragma unroll
        for (int i = 0; i < 2; ++i) {
            float xv[4];
            *(float4*)&xv[0] = *(const float4*)&as[ty * 2 + i][kk];
            #pragma unroll
            for (int j = 0; j < 4; ++j) {
                #pragma unroll
                for (int c = 0; c < 4; ++c)
                    acc[i][c] += xv[j] * wv[j][c];
            }
        }
    }
    #pragma unroll
    for (int i = 0; i < 2; ++i) {
        int v = node0 + ty * 2 + i;
        if (v < NN) {
            float di = dinv[v];
            float4 o;
            o.x = acc[i][0] * di; o.y = acc[i][1] * di;
            o.z = acc[i][2] * di; o.w = acc[i][3] * di;
            *(float4*)(g2 + (size_t)v * 32 + tx * 4) = o;
        }
    }
}

// ------- gather 32ch + fused norm/bias: z[v] = dinv*(g2[v]+Σg2[nbr]) + bg2
__global__ __launch_bounds__(256) void k_gather32(const float* __restrict__ g2,
        const int* __restrict__ csr, const unsigned int* __restrict__ row_ptr,
        const unsigned int* __restrict__ cnt, const float* __restrict__ dinv,
        const float* __restrict__ bg2, float* __restrict__ z) {
    int node = (blockIdx.x * 256 + threadIdx.x) >> 5;  // half-wave = node
    int c = threadIdx.x & 31;
    if (node >= NN) return;
    unsigned int s0 = row_ptr[node];
    unsigned int n = cnt[node];
    float sum = g2[(size_t)node * 32 + c];
    unsigned int i = s0, end = s0 + n;
    for (; i + 2 <= end; i += 2) {
        int a = csr[i], b = csr[i + 1];
        float va = g2[(size_t)a * 32 + c];
        float vb = g2[(size_t)b * 32 + c];
        sum += va + vb;
    }
    if (i < end) sum += g2[(size_t)csr[i] * 32 + c];
    z[(size_t)node * 32 + c] = sum * dinv[node] + bg2[c];
}

// ---------------- decode: per block 64 nodes x 128 cols ----------------
// recompute d = relu(z@Wf1+bf1) for the node tile (cheap), keep Wf2 slice
// LDS-resident, then a barrier-free 64-step K loop: out = relu(d@Wf2+bf2).
__global__ __launch_bounds__(256) void k_decode(const float* __restrict__ z,
        const float* __restrict__ Wf1, const float* __restrict__ bf1,
        const float* __restrict__ Wf2, const float* __restrict__ bf2,
        float* __restrict__ out) {
    __shared__ __align__(16) float z_s[64][36];
    __shared__ __align__(16) float dsh[64][68];
    __shared__ __align__(16) float w2s[64][128];   // w1s aliases the front
    float (* const w1s)[68] = (float (*)[68])&w2s[0][0];
    const int tid = threadIdx.x;
    const int cb = blockIdx.x & 7, nb = blockIdx.x >> 3;
    const int node0 = nb * 64, col0 = cb * 128;

    // stage z tile [64][32] (2 f4/thread) and Wf1 [32][64] (2 f4/thread)
    #pragma unroll
    for (int j = 0; j < 2; ++j) {
        int fi = tid + 256 * j;
        int v = fi >> 3, m4 = (fi & 7) * 4;
        float4 zz = make_float4(0.f, 0.f, 0.f, 0.f);
        if (node0 + v < NN) zz = *(const float4*)(z + (size_t)(node0 + v) * 32 + m4);
        *(float4*)&z_s[v][m4] = zz;
    }
    #pragma unroll
    for (int j = 0; j < 2; ++j) {
        int fi = tid + 256 * j;
        int r = fi >> 4, c4 = (fi & 15) * 4;
        *(float4*)&w1s[r][c4] = *(const float4*)(Wf1 + (size_t)r * 64 + c4);
    }
    // issue Wf2 slice loads early (8 f4/thread), consumed after d-compute
    float4 w2r[8];
    #pragma unroll
    for (int j = 0; j < 8; ++j) {
        int fi = tid + 256 * j;
        int r = fi >> 5, c4 = (fi & 31) * 4;
        w2r[j] = *(const float4*)(Wf2 + (size_t)r * 1024 + col0 + c4);
    }
    __syncthreads();

    // d-compute: thread (dtx cols, dty nodes): 4n x 4c
    {
        const int dtx = tid & 15, dty = tid >> 4;
        float acc[4][4] = {{0.f}};
        for (int m = 0; m < 32; m += 4) {
            float wv[4][4];
            #pragma unroll
            for (int j = 0; j < 4; ++j)
                *(float4*)&wv[j][0] = *(const float4*)&w1s[m + j][dtx * 4];
            #pragma unroll
            for (int i = 0; i < 4; ++i) {
                float zv[4];
                *(float4*)&zv[0] = *(const float4*)&z_s[dty * 4 + i][m];
                #pragma unroll
                for (int j = 0; j < 4; ++j) {
                    #pragma unroll
                    for (int c = 0; c < 4; ++c)
                        acc[i][c] += zv[j] * wv[j][c];
                }
            }
        }
        float4 b4 = *(const float4*)(bf1 + dtx * 4);
        #pragma unroll
        for (int i = 0; i < 4; ++i) {
            float4 dd;
            dd.x = fmaxf(acc[i][0] + b4.x, 0.f);
            dd.y = fmaxf(acc[i][1] + b4.y, 0.f);
            dd.z = fmaxf(acc[i][2] + b4.z, 0.f);
            dd.w = fmaxf(acc[i][3] + b4.w, 0.f);
            *(float4*)&dsh[dty * 4 + i][dtx * 4] = dd;
        }
    }
    __syncthreads();   // all w1s reads done
    // write Wf2 slice into LDS (overwrites w1s region)
    #pragma unroll
    for (int j = 0; j < 8; ++j) {
        int fi = tid + 256 * j;
        int r = fi >> 5, c4 = (fi & 31) * 4;
        *(float4*)&w2s[r][c4] = w2r[j];
    }
    __syncthreads();

    // main loop: out tile 64n x 128c, per-thread 8n x 4c, barrier-free
    const int tx = tid & 31, ty = tid >> 5;
    float acc[8][4] = {{0.f}};
    for (int kk = 0; kk < 64; kk += 4) {
        float wv[4][4];
        #pragma unroll
        for (int j = 0; j < 4; ++j)
            *(float4*)&wv[j][0] = *(const float4*)&w2s[kk + j][tx * 4];
        #pragma unroll
        for (int i = 0; i < 8; ++i) {
            float dv[4];
            *(float4*)&dv[0] = *(const float4*)&dsh[ty * 8 + i][kk];
            #pragma unroll
            for (int j = 0; j < 4; ++j) {
                #pragma unroll
                for (int c = 0; c < 4; ++c)
                    acc[i][c] += dv[j] * wv[j][c];
            }
        }
    }
    float4 b4 = *(const float4*)(bf2 + col0 + tx * 4);
    #pragma unroll
    for (int i = 0; i < 8; ++i) {
        int v = node0 + ty * 8 + i;
        if (v < NN) {
            float4 o;
            o.x = fmaxf(acc[i][0] + b4.x, 0.f);
            o.y = fmaxf(acc[i][1] + b4.y, 0.f);
            o.z = fmaxf(acc[i][2] + b4.z, 0.f);
            o.w = fmaxf(acc[i][3] + b4.w, 0.f);
            *(float4*)(out + (size_t)v * 1024 + col0 + tx * 4) = o;
        }
    }
}

extern "C" void kernel_launch(void* const* d_in, const int* in_sizes, int n_in,
                              void* d_out, int out_size, void* d_ws, size_t ws_size,
                              hipStream_t stream) {
    const float* x   = (const float*)d_in[0];
    const int* ei    = (const int*)d_in[1];
    const float* Wg1 = (const float*)d_in[2];
    const float* bg1 = (const float*)d_in[3];
    const float* Wg2 = (const float*)d_in[4];
    const float* bg2 = (const float*)d_in[5];
    const float* Wf1 = (const float*)d_in[6];
    const float* bf1 = (const float*)d_in[7];
    const float* Wf2 = (const float*)d_in[8];
    const float* bf2 = (const float*)d_in[9];
    float* out = (float*)d_out;
    float* ws  = (float*)d_ws;

    const int* src = ei;
    const int* dst = ei + EE;

    // ws scratch (26 MB): dinv | g2 | z
    float* dinv = ws;
    float* g2   = ws + NN;
    float* z    = ws + NN + 32 * NN;

    // d_out spare space used as scratch (all dead before k_decode writes out):
    float* g1 = out;                                  // 64N floats
    float* h  = out + (size_t)64 * NN;                // 64N floats
    int*      csr_src = (int*)(out + (size_t)128 * NN);        // E ints
    unsigned int* cnt     = (unsigned int*)(csr_src + EE);      // N
    unsigned int* row_ptr = cnt + NN;                           // N
    unsigned int* cursor  = row_ptr + NN;                       // N

    k_init  <<<(NN + 255) / 256, 256, 0, stream>>>(cnt);
    k_count <<<(EE + 255) / 256, 256, 0, stream>>>(dst, cnt);
    k_dinv  <<<(NN + 255) / 256, 256, 0, stream>>>(cnt, dinv);
    k_scan  <<<1, 1024, 0, stream>>>(cnt, row_ptr, cursor);
    k_fill  <<<(EE + 255) / 256, 256, 0, stream>>>(src, dst, cursor, csr_src);
    k_gemm1 <<<(NN + 127) / 128, 256, 0, stream>>>(x, Wg1, dinv, g1);
    k_gather64<<<(NN * 64 + 255) / 256, 256, 0, stream>>>(g1, csr_src, row_ptr, cnt, dinv, bg1, h);
    k_layer2<<<(NN + 63) / 64, 256, 0, stream>>>(h, Wg2, dinv, g2);
    k_gather32<<<(NN * 32 + 255) / 256, 256, 0, stream>>>(g2, csr_src, row_ptr, cnt, dinv, bg2, z);
    k_decode<<<8 * ((NN + 63) / 64), 256, 0, stream>>>(z, Wf1, bf1, Wf2, bf2, out);
}

// Round 5
// 858.927 us; speedup vs baseline: 10.6803x; 1.1984x over previous
//
#include <hip/hip_runtime.h>

#define NN 100000
#define EE 1600000

using bf16x8 = __attribute__((ext_vector_type(8))) short;
using f32x4  = __attribute__((ext_vector_type(4))) float;

static __device__ __forceinline__ unsigned short f2bh(float f) {
    unsigned int u = __float_as_uint(f);
    return (unsigned short)((u + 0x7FFFu + ((u >> 16) & 1u)) >> 16);
}
static __device__ __forceinline__ float bh2f(unsigned short h) {
    return __uint_as_float(((unsigned int)h) << 16);
}

// ---------------- degree count (no self loop; +1 applied in dinv) ----------
__global__ __launch_bounds__(256) void k_init(unsigned int* cnt) {
    int v = blockIdx.x * 256 + threadIdx.x;
    if (v < NN) cnt[v] = 0u;
}

__global__ __launch_bounds__(256) void k_count(const int* __restrict__ dst, unsigned int* cnt) {
    int e = blockIdx.x * 256 + threadIdx.x;
    if (e < EE) atomicAdd(&cnt[dst[e]], 1u);
}

__global__ __launch_bounds__(256) void k_dinv(const unsigned int* __restrict__ cnt, float* dinv) {
    int v = blockIdx.x * 256 + threadIdx.x;
    if (v < NN) dinv[v] = rsqrtf((float)(cnt[v] + 1u));
}

// ---------------- exclusive prefix scan (single workgroup, shfl-based) -----
__global__ __launch_bounds__(1024) void k_scan(const unsigned int* __restrict__ cnt,
        unsigned int* __restrict__ row_ptr, unsigned int* __restrict__ cursor) {
    __shared__ unsigned int wsum[16];
    __shared__ unsigned int carry_s;
    const int tid = threadIdx.x;
    const int lane = tid & 63, w = tid >> 6;
    if (tid == 0) carry_s = 0u;
    __syncthreads();
    for (int base = 0; base < NN; base += 1024) {
        int i = base + tid;
        unsigned int v = (i < NN) ? cnt[i] : 0u;
        unsigned int incl = v;
        #pragma unroll
        for (int off = 1; off < 64; off <<= 1) {
            unsigned int t = __shfl_up(incl, off, 64);
            if (lane >= off) incl += t;
        }
        if (lane == 63) wsum[w] = incl;
        __syncthreads();
        unsigned int woff = 0;
        #pragma unroll
        for (int j = 0; j < 16; ++j) woff += (j < w) ? wsum[j] : 0u;
        unsigned int c = carry_s;
        if (i < NN) {
            unsigned int excl = c + woff + incl - v;
            row_ptr[i] = excl;
            cursor[i] = excl;
        }
        __syncthreads();
        if (tid == 1023) carry_s = c + woff + incl;
        __syncthreads();
    }
}

// ---------------- CSR fill: csr_src grouped by dst ----------------
__global__ __launch_bounds__(256) void k_fill(const int* __restrict__ src,
        const int* __restrict__ dst, unsigned int* cursor, int* __restrict__ csr_src) {
    int e = blockIdx.x * 256 + threadIdx.x;
    if (e < EE) {
        int d = dst[e];
        unsigned int pos = atomicAdd(&cursor[d], 1u);
        csr_src[pos] = src[e];
    }
}

// ---------------- prep: Wg1 [1024][64] -> transposed split-bf16 [64][1024] --
__global__ __launch_bounds__(256) void k_prepW1(const float* __restrict__ W,
        unsigned short* __restrict__ wh, unsigned short* __restrict__ wl) {
    int t = blockIdx.x * 256 + threadIdx.x;       // 65536
    int k = t >> 6, c = t & 63;
    float f = W[k * 64 + c];
    unsigned short h = f2bh(f);
    wh[c * 1024 + k] = h;
    wl[c * 1024 + k] = f2bh(f - bh2f(h));
}

// ---------------- prep: Wf2 [64][1024] -> transposed split-bf16 [1024][64] --
__global__ __launch_bounds__(256) void k_prepW2(const float* __restrict__ W,
        unsigned short* __restrict__ wh, unsigned short* __restrict__ wl) {
    int t = blockIdx.x * 256 + threadIdx.x;       // 65536
    int k = t >> 10, c = t & 1023;
    float f = W[k * 1024 + c];
    unsigned short h = f2bh(f);
    wh[c * 64 + k] = h;
    wl[c * 64 + k] = f2bh(f - bh2f(h));
}

// ---------------- GEMM1 (MFMA split-bf16): g1 = (x @ Wg1) * dinv[row] -------
// block 256 thr = 4 waves; tile 128 nodes x 64 cols; K chunks of 64.
// wave (wm,wn): 64 nodes x 32 cols; frags: 4 m x 2 n; 3 MFMAs per frag pair.
__global__ __launch_bounds__(256) void k_gemm1(const float* __restrict__ x,
        const unsigned short* __restrict__ wg1h, const unsigned short* __restrict__ wg1l,
        const float* __restrict__ dinv, float* __restrict__ g1) {
    __shared__ __align__(16) unsigned short xh[128][72];
    __shared__ __align__(16) unsigned short xl[128][72];
    __shared__ __align__(16) unsigned short wh[64][72];
    __shared__ __align__(16) unsigned short wl[64][72];
    const int tid = threadIdx.x;
    const int lane = tid & 63, w = tid >> 6;
    const int wm = w & 1, wn = w >> 1;
    const int node0 = blockIdx.x * 128;
    const int l16 = lane & 15, g = lane >> 4;
    f32x4 acc[4][2] = {};
    for (int kc = 0; kc < 1024; kc += 64) {
        // stage x tile -> split bf16
        #pragma unroll
        for (int j = 0; j < 8; ++j) {
            int fi = tid + 256 * j;
            int v = fi >> 4, k4 = (fi & 15) * 4;
            float4 xv = make_float4(0.f, 0.f, 0.f, 0.f);
            if (node0 + v < NN) xv = *(const float4*)(x + (size_t)(node0 + v) * 1024 + kc + k4);
            unsigned short h0 = f2bh(xv.x), h1 = f2bh(xv.y), h2 = f2bh(xv.z), h3 = f2bh(xv.w);
            *(uint2*)&xh[v][k4] = make_uint2((unsigned)h0 | ((unsigned)h1 << 16),
                                             (unsigned)h2 | ((unsigned)h3 << 16));
            unsigned short l0 = f2bh(xv.x - bh2f(h0)), l1 = f2bh(xv.y - bh2f(h1));
            unsigned short l2 = f2bh(xv.z - bh2f(h2)), l3 = f2bh(xv.w - bh2f(h3));
            *(uint2*)&xl[v][k4] = make_uint2((unsigned)l0 | ((unsigned)l1 << 16),
                                             (unsigned)l2 | ((unsigned)l3 << 16));
        }
        // stage pre-transposed W slices (linear copies)
        #pragma unroll
        for (int j = 0; j < 2; ++j) {
            int fi = tid + 256 * j;
            int c = fi >> 3, k8 = (fi & 7) * 8;
            *(uint4*)&wh[c][k8] = *(const uint4*)(wg1h + (size_t)c * 1024 + kc + k8);
            *(uint4*)&wl[c][k8] = *(const uint4*)(wg1l + (size_t)c * 1024 + kc + k8);
        }
        __syncthreads();
        #pragma unroll
        for (int ks = 0; ks < 64; ks += 32) {
            const int k0 = ks + g * 8;
            bf16x8 ah[4], al[4], bh[2], bl[2];
            #pragma unroll
            for (int mf = 0; mf < 4; ++mf) {
                int r = wm * 64 + mf * 16 + l16;
                ah[mf] = *(const bf16x8*)&xh[r][k0];
                al[mf] = *(const bf16x8*)&xl[r][k0];
            }
            #pragma unroll
            for (int nf = 0; nf < 2; ++nf) {
                int c = wn * 32 + nf * 16 + l16;
                bh[nf] = *(const bf16x8*)&wh[c][k0];
                bl[nf] = *(const bf16x8*)&wl[c][k0];
            }
            #pragma unroll
            for (int mf = 0; mf < 4; ++mf)
                #pragma unroll
                for (int nf = 0; nf < 2; ++nf) {
                    acc[mf][nf] = __builtin_amdgcn_mfma_f32_16x16x32_bf16(ah[mf], bh[nf], acc[mf][nf], 0, 0, 0);
                    acc[mf][nf] = __builtin_amdgcn_mfma_f32_16x16x32_bf16(al[mf], bh[nf], acc[mf][nf], 0, 0, 0);
                    acc[mf][nf] = __builtin_amdgcn_mfma_f32_16x16x32_bf16(ah[mf], bl[nf], acc[mf][nf], 0, 0, 0);
                }
        }
        __syncthreads();
    }
    // D: row = 4*(lane>>4)+r, col = lane&15  (per m-frag/n-frag)
    #pragma unroll
    for (int mf = 0; mf < 4; ++mf) {
        #pragma unroll
        for (int r = 0; r < 4; ++r) {
            int node = node0 + wm * 64 + mf * 16 + g * 4 + r;
            if (node < NN) {
                float di = dinv[node];
                #pragma unroll
                for (int nf = 0; nf < 2; ++nf) {
                    int col = wn * 32 + nf * 16 + l16;
                    g1[(size_t)node * 64 + col] = acc[mf][nf][r] * di;
                }
            }
        }
    }
}

// ------- gather 64ch + fused norm/bias/relu ---------------------------------
__global__ __launch_bounds__(256) void k_gather64(const float* __restrict__ g1,
        const int* __restrict__ csr, const unsigned int* __restrict__ row_ptr,
        const unsigned int* __restrict__ cnt, const float* __restrict__ dinv,
        const float* __restrict__ bg1, float* __restrict__ h) {
    int wv = (blockIdx.x * 256 + threadIdx.x) >> 6;   // wave = node
    int lane = threadIdx.x & 63;
    if (wv >= NN) return;
    unsigned int s0 = row_ptr[wv];
    unsigned int n = cnt[wv];
    float sum = g1[(size_t)wv * 64 + lane];           // self loop
    unsigned int i = s0, end = s0 + n;
    for (; i + 2 <= end; i += 2) {
        int a = csr[i], b = csr[i + 1];
        float va = g1[(size_t)a * 64 + lane];
        float vb = g1[(size_t)b * 64 + lane];
        sum += va + vb;
    }
    if (i < end) sum += g1[(size_t)csr[i] * 64 + lane];
    h[(size_t)wv * 64 + lane] = fmaxf(sum * dinv[wv] + bg1[lane], 0.f);
}

// ---------------- layer2 GEMM (fp32, tiny): g2 = (h @ Wg2) * dinv[row] ------
__global__ __launch_bounds__(256) void k_layer2(const float* __restrict__ h,
        const float* __restrict__ Wg2, const float* __restrict__ dinv,
        float* __restrict__ g2) {
    __shared__ __align__(16) float as[64][68];
    __shared__ __align__(16) float wsh[64][32];
    const int tid = threadIdx.x;
    const int node0 = blockIdx.x * 64;
    {
        const int lr = tid >> 4, lk = (tid & 15) * 4;
        #pragma unroll
        for (int l = 0; l < 4; ++l) {
            int r = lr + l * 16, v = node0 + r;
            float4 a = make_float4(0.f, 0.f, 0.f, 0.f);
            if (v < NN) a = *(const float4*)(h + (size_t)v * 64 + lk);
            *(float4*)&as[r][lk] = a;
        }
        const int wr = tid >> 3, wk = (tid & 7) * 4;
        #pragma unroll
        for (int l = 0; l < 2; ++l) {
            int r = wr + l * 32;
            *(float4*)&wsh[r][wk] = *(const float4*)(Wg2 + (size_t)r * 32 + wk);
        }
    }
    __syncthreads();
    const int tx = tid & 7, ty = tid >> 3;
    float acc[2][4] = {{0.f}};
    for (int kk = 0; kk < 64; kk += 4) {
        float wv[4][4];
        #pragma unroll
        for (int j = 0; j < 4; ++j)
            *(float4*)&wv[j][0] = *(const float4*)&wsh[kk + j][tx * 4];
        #pragma unroll
        for (int i = 0; i < 2; ++i) {
            float xv[4];
            *(float4*)&xv[0] = *(const float4*)&as[ty * 2 + i][kk];
            #pragma unroll
            for (int j = 0; j < 4; ++j) {
                #pragma unroll
                for (int c = 0; c < 4; ++c)
                    acc[i][c] += xv[j] * wv[j][c];
            }
        }
    }
    #pragma unroll
    for (int i = 0; i < 2; ++i) {
        int v = node0 + ty * 2 + i;
        if (v < NN) {
            float di = dinv[v];
            float4 o;
            o.x = acc[i][0] * di; o.y = acc[i][1] * di;
            o.z = acc[i][2] * di; o.w = acc[i][3] * di;
            *(float4*)(g2 + (size_t)v * 32 + tx * 4) = o;
        }
    }
}

// ------- gather 32ch + fused norm/bias --------------------------------------
__global__ __launch_bounds__(256) void k_gather32(const float* __restrict__ g2,
        const int* __restrict__ csr, const unsigned int* __restrict__ row_ptr,
        const unsigned int* __restrict__ cnt, const float* __restrict__ dinv,
        const float* __restrict__ bg2, float* __restrict__ z) {
    int node = (blockIdx.x * 256 + threadIdx.x) >> 5;  // half-wave = node
    int c = threadIdx.x & 31;
    if (node >= NN) return;
    unsigned int s0 = row_ptr[node];
    unsigned int n = cnt[node];
    float sum = g2[(size_t)node * 32 + c];
    unsigned int i = s0, end = s0 + n;
    for (; i + 2 <= end; i += 2) {
        int a = csr[i], b = csr[i + 1];
        float va = g2[(size_t)a * 32 + c];
        float vb = g2[(size_t)b * 32 + c];
        sum += va + vb;
    }
    if (i < end) sum += g2[(size_t)csr[i] * 32 + c];
    z[(size_t)node * 32 + c] = sum * dinv[node] + bg2[c];
}

// ---------------- decode (MFMA): 64 nodes x full 1024 cols per block --------
// phase1: d = relu(z@Wf1+bf1) fp32 in LDS; phase2: d -> reg A-frags (split);
// phase3: 8 col-chunks: stage pre-split Wf2^T slice, MFMA, write full rows.
__global__ __launch_bounds__(256) void k_decode(const float* __restrict__ z,
        const float* __restrict__ Wf1, const float* __restrict__ bf1,
        const unsigned short* __restrict__ w2hg, const unsigned short* __restrict__ w2lg,
        const float* __restrict__ bf2, float* __restrict__ out) {
    __shared__ __align__(16) unsigned char smem[36864];
    float (*dsh)[68] = (float (*)[68])smem;                          // 64x68 f
    float (*zs)[36]  = (float (*)[36])(smem + 17408);                // 64x36 f
    float (*w1s)[64] = (float (*)[64])(smem + 17408 + 9216);         // 32x64 f
    unsigned short (*w2h)[72] = (unsigned short (*)[72])smem;        // 128x72 u16
    unsigned short (*w2l)[72] = (unsigned short (*)[72])(smem + 18432);
    const int tid = threadIdx.x;
    const int lane = tid & 63, w = tid >> 6;
    const int l16 = lane & 15, g = lane >> 4;
    const int node0 = blockIdx.x * 64;

    // phase 1a: stage z [64][32] and Wf1 [32][64]
    #pragma unroll
    for (int j = 0; j < 2; ++j) {
        int fi = tid + 256 * j;
        int v = fi >> 3, m4 = (fi & 7) * 4;
        float4 zz = make_float4(0.f, 0.f, 0.f, 0.f);
        if (node0 + v < NN) zz = *(const float4*)(z + (size_t)(node0 + v) * 32 + m4);
        *(float4*)&zs[v][m4] = zz;
    }
    #pragma unroll
    for (int j = 0; j < 2; ++j) {
        int fi = tid + 256 * j;
        int r = fi >> 4, c4 = (fi & 15) * 4;
        *(float4*)&w1s[r][c4] = *(const float4*)(Wf1 + (size_t)r * 64 + c4);
    }
    __syncthreads();

    // phase 1b: d = relu(z @ Wf1 + bf1) -> dsh (fp32)
    {
        const int dtx = tid & 15, dty = tid >> 4;
        float acc[4][4] = {{0.f}};
        for (int m = 0; m < 32; m += 4) {
            float wv[4][4];
            #pragma unroll
            for (int j = 0; j < 4; ++j)
                *(float4*)&wv[j][0] = *(const float4*)&w1s[m + j][dtx * 4];
            #pragma unroll
            for (int i = 0; i < 4; ++i) {
                float zv[4];
                *(float4*)&zv[0] = *(const float4*)&zs[dty * 4 + i][m];
                #pragma unroll
                for (int j = 0; j < 4; ++j) {
                    #pragma unroll
                    for (int c = 0; c < 4; ++c)
                        acc[i][c] += zv[j] * wv[j][c];
                }
            }
        }
        float4 b4 = *(const float4*)(bf1 + dtx * 4);
        #pragma unroll
        for (int i = 0; i < 4; ++i) {
            float4 dd;
            dd.x = fmaxf(acc[i][0] + b4.x, 0.f);
            dd.y = fmaxf(acc[i][1] + b4.y, 0.f);
            dd.z = fmaxf(acc[i][2] + b4.z, 0.f);
            dd.w = fmaxf(acc[i][3] + b4.w, 0.f);
            *(float4*)&dsh[dty * 4 + i][dtx * 4] = dd;
        }
    }
    __syncthreads();

    // phase 2: per-wave A-frags in registers (16 nodes/wave, split-bf16)
    bf16x8 ah[2], al[2];
    {
        int row = w * 16 + l16;
        #pragma unroll
        for (int s = 0; s < 2; ++s) {
            int k0 = s * 32 + g * 8;
            float4 f0 = *(float4*)&dsh[row][k0];
            float4 f1 = *(float4*)&dsh[row][k0 + 4];
            float fv[8] = {f0.x, f0.y, f0.z, f0.w, f1.x, f1.y, f1.z, f1.w};
            bf16x8 hv, lv;
            #pragma unroll
            for (int e = 0; e < 8; ++e) {
                unsigned short hh = f2bh(fv[e]);
                hv[e] = (short)hh;
                lv[e] = (short)f2bh(fv[e] - bh2f(hh));
            }
            ah[s] = hv; al[s] = lv;
        }
    }
    __syncthreads();   // dsh dead; w2 may now overwrite

    // phase 3: col chunks of 128
    for (int ch = 0; ch < 8; ++ch) {
        const int col0 = ch * 128;
        #pragma unroll
        for (int j = 0; j < 4; ++j) {
            int fi = tid + 256 * j;
            int c = fi >> 3, k8 = (fi & 7) * 8;
            *(uint4*)&w2h[c][k8] = *(const uint4*)(w2hg + (size_t)(col0 + c) * 64 + k8);
            *(uint4*)&w2l[c][k8] = *(const uint4*)(w2lg + (size_t)(col0 + c) * 64 + k8);
        }
        __syncthreads();
        f32x4 acc[8] = {};
        #pragma unroll
        for (int nf = 0; nf < 8; ++nf) {
            int c = nf * 16 + l16;
            #pragma unroll
            for (int s = 0; s < 2; ++s) {
                int k0 = s * 32 + g * 8;
                bf16x8 bh = *(const bf16x8*)&w2h[c][k0];
                bf16x8 bl = *(const bf16x8*)&w2l[c][k0];
                acc[nf] = __builtin_amdgcn_mfma_f32_16x16x32_bf16(ah[s], bh, acc[nf], 0, 0, 0);
                acc[nf] = __builtin_amdgcn_mfma_f32_16x16x32_bf16(al[s], bh, acc[nf], 0, 0, 0);
                acc[nf] = __builtin_amdgcn_mfma_f32_16x16x32_bf16(ah[s], bl, acc[nf], 0, 0, 0);
            }
        }
        #pragma unroll
        for (int nf = 0; nf < 8; ++nf) {
            int col = col0 + nf * 16 + l16;
            float b = bf2[col];
            #pragma unroll
            for (int r = 0; r < 4; ++r) {
                int node = node0 + w * 16 + g * 4 + r;
                if (node < NN)
                    out[(size_t)node * 1024 + col] = fmaxf(acc[nf][r] + b, 0.f);
            }
        }
        __syncthreads();
    }
}

extern "C" void kernel_launch(void* const* d_in, const int* in_sizes, int n_in,
                              void* d_out, int out_size, void* d_ws, size_t ws_size,
                              hipStream_t stream) {
    const float* x   = (const float*)d_in[0];
    const int* ei    = (const int*)d_in[1];
    const float* Wg1 = (const float*)d_in[2];
    const float* bg1 = (const float*)d_in[3];
    const float* Wg2 = (const float*)d_in[4];
    const float* bg2 = (const float*)d_in[5];
    const float* Wf1 = (const float*)d_in[6];
    const float* bf1 = (const float*)d_in[7];
    const float* Wf2 = (const float*)d_in[8];
    const float* bf2 = (const float*)d_in[9];
    float* out = (float*)d_out;
    float* ws  = (float*)d_ws;

    const int* src = ei;
    const int* dst = ei + EE;

    // ws (26 MB, proven available): dinv | g2 | z ; Wf2T tables overlay g2
    // after k_gather32 (g2 dead by then).
    float* dinv = ws;
    float* g2   = ws + NN;
    float* z    = ws + NN + 32 * NN;
    unsigned short* wf2h = (unsigned short*)g2;            // 64K u16
    unsigned short* wf2l = wf2h + 64 * 1024;               // 64K u16

    // d_out scratch (all dead before k_decode writes out):
    float* g1 = out;                                       // 64N floats
    float* h  = out + (size_t)64 * NN;                     // 64N floats
    unsigned short* wg1h = (unsigned short*)h;             // 64K u16 (dead
    unsigned short* wg1l = wg1h + 64 * 1024;               //  before h write)
    int*      csr_src = (int*)(out + (size_t)128 * NN);    // E ints
    unsigned int* cnt     = (unsigned int*)(csr_src + EE); // N
    unsigned int* row_ptr = cnt + NN;                      // N
    unsigned int* cursor  = row_ptr + NN;                  // N

    k_init  <<<(NN + 255) / 256, 256, 0, stream>>>(cnt);
    k_count <<<(EE + 255) / 256, 256, 0, stream>>>(dst, cnt);
    k_dinv  <<<(NN + 255) / 256, 256, 0, stream>>>(cnt, dinv);
    k_scan  <<<1, 1024, 0, stream>>>(cnt, row_ptr, cursor);
    k_fill  <<<(EE + 255) / 256, 256, 0, stream>>>(src, dst, cursor, csr_src);
    k_prepW1<<<256, 256, 0, stream>>>(Wg1, wg1h, wg1l);
    k_gemm1 <<<(NN + 127) / 128, 256, 0, stream>>>(x, wg1h, wg1l, dinv, g1);
    k_gather64<<<(NN * 64 + 255) / 256, 256, 0, stream>>>(g1, csr_src, row_ptr, cnt, dinv, bg1, h);
    k_layer2<<<(NN + 63) / 64, 256, 0, stream>>>(h, Wg2, dinv, g2);
    k_gather32<<<(NN * 32 + 255) / 256, 256, 0, stream>>>(g2, csr_src, row_ptr, cnt, dinv, bg2, z);
    k_prepW2<<<256, 256, 0, stream>>>(Wf2, wf2h, wf2l);
    k_decode<<<(NN + 63) / 64, 256, 0, stream>>>(z, Wf1, bf1, wf2h, wf2l, bf2, out);
}